// Round 3
// baseline (104.371 us; speedup 1.0000x reference)
//
#include <hip/hip_runtime.h>
#include <math.h>

#define BLK 100          // BLOCK
#define NF  128          // N_freqs
#define NTOT (NF * BLK)  // 12800
#define RPB 13           // rows per half-wave (8 half-waves x 13 = 104 >= 100)

// One workgroup per frequency block. Matrix lives in REGISTERS:
// thread (rb = tid>>5 in [0,8), g = tid&31, active g<25) owns rows
// rb*13 .. rb*13+12, columns 4g..4g+3  => float4 regs[13].
// Per step k: pivot row via LDS (double-buffered), fac column via
// v_readlane (in-register broadcast). 1 barrier per step.
__global__ __launch_bounds__(256) void lu_logdet_kernel(const float* __restrict__ w,
                                                        const float* __restrict__ L,
                                                        float* __restrict__ out) {
    __shared__ float4 pivbuf[2][25];
    __shared__ float  rinvbuf[2];
    __shared__ float  diag[BLK];
    __shared__ float  red[256];
    __shared__ int    negs[256];

    const int f   = blockIdx.x;
    const int tid = threadIdx.x;
    const int rb  = tid >> 5;        // half-wave index 0..7
    const int g   = tid & 31;        // colgroup, active if g < 25
    const int r0  = rb * RPB;
    const bool act = (g < 25);

    float4 regs[RPB];

    // ---- load diag block f, fused transform: M[r][c] = s_r*D[r][c] + (r==c ? 1-s_r : 0)
    const float* base = L + (size_t)f * BLK * NTOT + (size_t)f * BLK;
    #pragma unroll
    for (int j = 0; j < RPB; ++j) {
        const int r = r0 + j;
        float4 m = make_float4(0.f, 0.f, 0.f, 0.f);
        if (act && r < BLK) {
            const int c0 = 4 * g;
            const float4 v = *reinterpret_cast<const float4*>(base + (size_t)r * NTOT + c0);
            const float sv = 1.0f / (1.0f + expf(-w[f * BLK + r]));
            const float ds = 1.0f - sv;
            m.x = sv * v.x + ((c0 + 0) == r ? ds : 0.0f);
            m.y = sv * v.y + ((c0 + 1) == r ? ds : 0.0f);
            m.z = sv * v.z + ((c0 + 2) == r ? ds : 0.0f);
            m.w = sv * v.w + ((c0 + 3) == r ? ds : 0.0f);
        }
        regs[j] = m;
    }

    // ---- prologue: publish pivot row 0
    if (rb == 0 && act) {
        pivbuf[0][g] = regs[0];
        if (g == 0) { rinvbuf[0] = 1.0f / regs[0].x; diag[0] = regs[0].x; }
    }
    __syncthreads();

    // CX = component holding col k, CNX = component holding col k+1 (for case k&3)
#define STEP_BODY(CX, CNX)                                                    \
    {                                                                         \
        _Pragma("unroll")                                                     \
        for (int j = 0; j < RPB; ++j) {                                       \
            const int r = r0 + j;                                             \
            const float xv  = regs[j].CX;                                     \
            const float flo = __uint_as_float(                                \
                __builtin_amdgcn_readlane(__float_as_uint(xv), src));         \
            const float fhi = __uint_as_float(                                \
                __builtin_amdgcn_readlane(__float_as_uint(xv), src + 32));    \
            const float cv  = (tid & 32) ? fhi : flo;                         \
            const float fac = (r > k && r < BLK) ? cv * rinv : 0.0f;          \
            regs[j].x -= fac * p4.x;                                          \
            regs[j].y -= fac * p4.y;                                          \
            regs[j].z -= fac * p4.z;                                          \
            regs[j].w -= fac * p4.w;                                          \
            if (r == kn) {                                                    \
                if (act) pivbuf[nb][g] = regs[j];                             \
                if (g == (kn >> 2)) {                                         \
                    const float dnew = regs[j].CNX;                           \
                    rinvbuf[nb] = 1.0f / dnew;                                \
                    diag[kn]    = dnew;                                       \
                }                                                             \
            }                                                                 \
        }                                                                     \
    }

    // ---- right-looking GE, no pivoting
    for (int k = 0; k < BLK - 1; ++k) {
        const int b   = k & 1;
        const int nb  = b ^ 1;
        const int kn  = k + 1;
        const int src = k >> 2;                  // lane owning col k (per half-wave)
        const float rinv = rinvbuf[b];
        float4 p4 = make_float4(0.f, 0.f, 0.f, 0.f);
        if (act) p4 = pivbuf[b][g];

        switch (k & 3) {
            case 0: STEP_BODY(x, y) break;
            case 1: STEP_BODY(y, z) break;
            case 2: STEP_BODY(z, w) break;
            case 3: STEP_BODY(w, x) break;
        }
        __syncthreads();
    }
#undef STEP_BODY

    // ---- logdet from U diagonal (collected in diag[] during the loop)
    float lsum = 0.0f;
    int   lneg = 0;
    if (tid < BLK) {
        const float d = diag[tid];
        lsum = logf(fabsf(d));                   // d==0 -> -inf -> caught below
        lneg = (d < 0.0f) ? 1 : 0;
    }
    red[tid]  = lsum;
    negs[tid] = lneg;
    __syncthreads();
    for (int s = 128; s > 0; s >>= 1) {
        if (tid < s) { red[tid] += red[tid + s]; negs[tid] += negs[tid + s]; }
        __syncthreads();
    }
    if (tid == 0) {
        float ld = red[0];
        if ((negs[0] & 1) || !isfinite(ld)) ld = __int_as_float(0x7fc00000);  // NaN
        out[1 + f] = ld;
    }
}

// Sum the 128 logdets into out[0] (NaN propagates, matching jnp.sum of where(...))
__global__ __launch_bounds__(128) void sum_kernel(float* __restrict__ out) {
    const int t = threadIdx.x;
    float v = out[1 + t];
    v += __shfl_down(v, 32);
    v += __shfl_down(v, 16);
    v += __shfl_down(v, 8);
    v += __shfl_down(v, 4);
    v += __shfl_down(v, 2);
    v += __shfl_down(v, 1);
    __shared__ float ws2[2];
    if ((t & 63) == 0) ws2[t >> 6] = v;
    __syncthreads();
    if (t == 0) out[0] = ws2[0] + ws2[1];
}

extern "C" void kernel_launch(void* const* d_in, const int* in_sizes, int n_in,
                              void* d_out, int out_size, void* d_ws, size_t ws_size,
                              hipStream_t stream) {
    const float* w = (const float*)d_in[0];   // weights (12800,) f32
    const float* L = (const float*)d_in[1];   // L_kernel (12800,12800) f32
    float* out = (float*)d_out;               // [0]=sum, [1..128]=logdets
    lu_logdet_kernel<<<NF, 256, 0, stream>>>(w, L, out);
    sum_kernel<<<1, 128, 0, stream>>>(out);
}

// Round 4
// 39.423 us; speedup vs baseline: 2.6475x; 2.6475x over previous
//
#include <hip/hip_runtime.h>
#include <math.h>

#define BLK 100          // BLOCK
#define NF  128          // N_freqs
#define NTOT (NF * BLK)  // 12800
#define P   104          // LDS pitch (floats): rows 16B-aligned (416B = 26x16B)

__device__ __forceinline__ float rdlane(float x, int l) {
    return __uint_as_float(__builtin_amdgcn_readlane(__float_as_uint(x), l));
}

#define LD4(r, c4) (*reinterpret_cast<float4*>(&a[(r) * P + 4 * (c4)]))

__device__ __forceinline__ float4 fnma4(float4 v, float s, const float4 p) {
    v.x -= s * p.x; v.y -= s * p.y; v.z -= s * p.z; v.w -= s * p.w; return v;
}

// One workgroup per frequency block: build M = s*D + (1-s)*I in LDS, then
// blocked (rank-4) right-looking non-pivoted LU. Per phase k0 (k0 % 4 == 0):
//   panel: wave 0 lanes 0..24 update pivot rows k0+1..3 (readlane broadcasts,
//          wave-synchronous, no barrier), record diag d0..d3.
//   sweep: all waves apply fused rank-4 update to rows >= k0+4, column
//          groups > gp only (dead columns skipped). 2 barriers per phase.
__global__ __launch_bounds__(256) void lu_logdet_kernel(const float* __restrict__ w,
                                                        const float* __restrict__ L,
                                                        float* __restrict__ out) {
    __shared__ float a[BLK * P];
    __shared__ float diag[BLK];
    __shared__ float red[256];
    __shared__ int   negs[256];

    const int f    = blockIdx.x;
    const int tid  = threadIdx.x;
    const int wave = tid >> 6;
    const int lane = tid & 63;
    const int half = lane >> 5;      // 0: row i, 1: row i+1 (sweep mapping)
    const int g    = lane & 31;      // float4 column group, active if g < 25

    // ---- load diag block f, fused transform: M[r][c] = s_r*D[r][c] + (r==c ? 1-s_r : 0)
    const float* base = L + (size_t)f * BLK * NTOT + (size_t)f * BLK;
    for (int q = tid; q < BLK * 25; q += 256) {        // 25 float4 per row
        const int r  = q / 25;
        const int c0 = (q - r * 25) * 4;
        const float4 v = *reinterpret_cast<const float4*>(base + (size_t)r * NTOT + c0);
        const float sv = 1.0f / (1.0f + expf(-w[f * BLK + r]));
        const float ds = 1.0f - sv;
        float4 m;
        m.x = sv * v.x + ((c0 + 0) == r ? ds : 0.0f);
        m.y = sv * v.y + ((c0 + 1) == r ? ds : 0.0f);
        m.z = sv * v.z + ((c0 + 2) == r ? ds : 0.0f);
        m.w = sv * v.w + ((c0 + 3) == r ? ds : 0.0f);
        *reinterpret_cast<float4*>(&a[r * P + c0]) = m;
    }
    __syncthreads();

    for (int k0 = 0; k0 < BLK; k0 += 4) {
        const int gp = k0 >> 2;      // panel column group (k0 % 4 == 0)

        // ---- panel: wave 0, lanes 0..24 update pivot rows k0+1..k0+3
        if (wave == 0 && lane < 25) {
            float4 p0 = LD4(k0 + 0, lane);
            float4 v1 = LD4(k0 + 1, lane);
            float4 v2 = LD4(k0 + 2, lane);
            float4 v3 = LD4(k0 + 3, lane);
            const float d0 = rdlane(p0.x, gp), r0i = 1.0f / d0;
            float fc;
            fc = rdlane(v1.x, gp) * r0i;  v1 = fnma4(v1, fc, p0);   // row k0+1 done
            const float d1 = rdlane(v1.y, gp), r1i = 1.0f / d1;
            fc = rdlane(v2.x, gp) * r0i;  v2 = fnma4(v2, fc, p0);
            fc = rdlane(v2.y, gp) * r1i;  v2 = fnma4(v2, fc, v1);   // row k0+2 done
            const float d2 = rdlane(v2.z, gp), r2i = 1.0f / d2;
            fc = rdlane(v3.x, gp) * r0i;  v3 = fnma4(v3, fc, p0);
            fc = rdlane(v3.y, gp) * r1i;  v3 = fnma4(v3, fc, v1);
            fc = rdlane(v3.z, gp) * r2i;  v3 = fnma4(v3, fc, v2);   // row k0+3 done
            const float d3 = rdlane(v3.w, gp);
            LD4(k0 + 1, lane) = v1;
            LD4(k0 + 2, lane) = v2;
            LD4(k0 + 3, lane) = v3;
            if (lane == 0) {
                diag[k0 + 0] = d0; diag[k0 + 1] = d1;
                diag[k0 + 2] = d2; diag[k0 + 3] = d3;
            }
        }
        __syncthreads();

        // ---- sweep: rank-4 update of rows >= k0+4, column groups > gp
        const int i0 = k0 + 4 + 2 * wave + half;
        if (g > gp && g < 25 && i0 < BLK) {
            const float4 pp0 = LD4(k0 + 0, gp);   // broadcast reads (same addr)
            const float4 pp1 = LD4(k0 + 1, gp);
            const float4 pp2 = LD4(k0 + 2, gp);
            const float4 pp3 = LD4(k0 + 3, gp);
            const float r0i = 1.0f / pp0.x;
            const float r1i = 1.0f / pp1.y;
            const float r2i = 1.0f / pp2.z;
            const float r3i = 1.0f / pp3.w;
            const float4 P0 = LD4(k0 + 0, g);     // pivot rows cached in regs
            const float4 P1 = LD4(k0 + 1, g);
            const float4 P2 = LD4(k0 + 2, g);
            const float4 P3 = LD4(k0 + 3, g);

#define FACS(pan, f0, f1, f2, f3)                                             \
            const float f0 = pan.x * r0i;                                     \
            const float f1 = (pan.y - f0 * pp0.y) * r1i;                      \
            const float f2 = (pan.z - f0 * pp0.z - f1 * pp1.z) * r2i;         \
            const float f3 = (pan.w - f0 * pp0.w - f1 * pp1.w - f2 * pp2.w) * r3i;

            int i = i0;
            for (; i + 8 < BLK; i += 16) {
                const int i2 = i + 8;
                float4 panA = LD4(i,  gp);
                float4 panB = LD4(i2, gp);
                float4 vA = LD4(i,  g);
                float4 vB = LD4(i2, g);
                FACS(panA, a0, a1, a2, a3)
                FACS(panB, b0, b1, b2, b3)
                vA = fnma4(vA, a0, P0); vA = fnma4(vA, a1, P1);
                vA = fnma4(vA, a2, P2); vA = fnma4(vA, a3, P3);
                vB = fnma4(vB, b0, P0); vB = fnma4(vB, b1, P1);
                vB = fnma4(vB, b2, P2); vB = fnma4(vB, b3, P3);
                LD4(i,  g) = vA;
                LD4(i2, g) = vB;
            }
            for (; i < BLK; i += 8) {
                float4 pan = LD4(i, gp);
                float4 v = LD4(i, g);
                FACS(pan, c0, c1, c2, c3)
                v = fnma4(v, c0, P0); v = fnma4(v, c1, P1);
                v = fnma4(v, c2, P2); v = fnma4(v, c3, P3);
                LD4(i, g) = v;
            }
#undef FACS
        }
        __syncthreads();
    }

    // ---- logdet from U diagonal (collected in diag[] during the loop)
    float lsum = 0.0f;
    int   lneg = 0;
    if (tid < BLK) {
        const float d = diag[tid];
        lsum = logf(fabsf(d));                   // d==0 -> -inf -> caught below
        lneg = (d < 0.0f) ? 1 : 0;
    }
    red[tid]  = lsum;
    negs[tid] = lneg;
    __syncthreads();
    for (int s = 128; s > 0; s >>= 1) {
        if (tid < s) { red[tid] += red[tid + s]; negs[tid] += negs[tid + s]; }
        __syncthreads();
    }
    if (tid == 0) {
        float ld = red[0];
        if ((negs[0] & 1) || !isfinite(ld)) ld = __int_as_float(0x7fc00000);  // NaN
        out[1 + f] = ld;
    }
}

// Sum the 128 logdets into out[0] (NaN propagates, matching jnp.sum of where(...))
__global__ __launch_bounds__(128) void sum_kernel(float* __restrict__ out) {
    const int t = threadIdx.x;
    float v = out[1 + t];
    v += __shfl_down(v, 32);
    v += __shfl_down(v, 16);
    v += __shfl_down(v, 8);
    v += __shfl_down(v, 4);
    v += __shfl_down(v, 2);
    v += __shfl_down(v, 1);
    __shared__ float ws2[2];
    if ((t & 63) == 0) ws2[t >> 6] = v;
    __syncthreads();
    if (t == 0) out[0] = ws2[0] + ws2[1];
}

extern "C" void kernel_launch(void* const* d_in, const int* in_sizes, int n_in,
                              void* d_out, int out_size, void* d_ws, size_t ws_size,
                              hipStream_t stream) {
    const float* w = (const float*)d_in[0];   // weights (12800,) f32
    const float* L = (const float*)d_in[1];   // L_kernel (12800,12800) f32
    float* out = (float*)d_out;               // [0]=sum, [1..128]=logdets
    lu_logdet_kernel<<<NF, 256, 0, stream>>>(w, L, out);
    sum_kernel<<<1, 128, 0, stream>>>(out);
}

// Round 5
// 37.643 us; speedup vs baseline: 2.7727x; 1.0473x over previous
//
#include <hip/hip_runtime.h>
#include <math.h>

#define BLK 100          // BLOCK
#define NF  128          // N_freqs
#define NTOT (NF * BLK)  // 12800
#define P   104          // LDS pitch (floats): rows 16B-aligned (416B = 26x16B)

__device__ __forceinline__ float rdlane(float x, int l) {
    return __uint_as_float(__builtin_amdgcn_readlane(__float_as_uint(x), l));
}

__device__ __forceinline__ float4 fnma4(float4 v, float s, const float4 p) {
    v.x -= s * p.x; v.y -= s * p.y; v.z -= s * p.z; v.w -= s * p.w; return v;
}

#define LD4(r, c4) (*reinterpret_cast<float4*>(&a[(r) * P + 4 * (c4)]))

// Panel factor at k0 (k0 % 4 == 0): update pivot rows k0+1..k0+3 against row
// k0, record diag[k0..k0+3]. Runs on wave 0, lanes 0..24 (lane = col group).
__device__ __forceinline__ void panel4(float* a, float* diag, const int k0, const int lane) {
    const int gp = k0 >> 2;
    float4 p0 = LD4(k0 + 0, lane);
    float4 v1 = LD4(k0 + 1, lane);
    float4 v2 = LD4(k0 + 2, lane);
    float4 v3 = LD4(k0 + 3, lane);
    const float d0 = rdlane(p0.x, gp), r0i = 1.0f / d0;
    float fc;
    fc = rdlane(v1.x, gp) * r0i;  v1 = fnma4(v1, fc, p0);   // row k0+1 done
    const float d1 = rdlane(v1.y, gp), r1i = 1.0f / d1;
    fc = rdlane(v2.x, gp) * r0i;  v2 = fnma4(v2, fc, p0);
    fc = rdlane(v2.y, gp) * r1i;  v2 = fnma4(v2, fc, v1);   // row k0+2 done
    const float d2 = rdlane(v2.z, gp), r2i = 1.0f / d2;
    fc = rdlane(v3.x, gp) * r0i;  v3 = fnma4(v3, fc, p0);
    fc = rdlane(v3.y, gp) * r1i;  v3 = fnma4(v3, fc, v1);
    fc = rdlane(v3.z, gp) * r2i;  v3 = fnma4(v3, fc, v2);   // row k0+3 done
    const float d3 = rdlane(v3.w, gp);
    LD4(k0 + 1, lane) = v1;
    LD4(k0 + 2, lane) = v2;
    LD4(k0 + 3, lane) = v3;
    if (lane == 0) {
        diag[k0 + 0] = d0; diag[k0 + 1] = d1;
        diag[k0 + 2] = d2; diag[k0 + 3] = d3;
    }
}

struct Piv4 {
    float4 pp0, pp1, pp2, pp3;   // panel column group gp of pivot rows
    float4 P0, P1, P2, P3;       // this lane's column group g of pivot rows
    float  r0i, r1i, r2i, r3i;
};

__device__ __forceinline__ Piv4 load_piv(float* a, const int k0, const int gp, const int g) {
    Piv4 p;
    p.pp0 = LD4(k0 + 0, gp); p.pp1 = LD4(k0 + 1, gp);
    p.pp2 = LD4(k0 + 2, gp); p.pp3 = LD4(k0 + 3, gp);
    p.r0i = 1.0f / p.pp0.x;  p.r1i = 1.0f / p.pp1.y;
    p.r2i = 1.0f / p.pp2.z;  p.r3i = 1.0f / p.pp3.w;
    p.P0  = LD4(k0 + 0, g);  p.P1  = LD4(k0 + 1, g);
    p.P2  = LD4(k0 + 2, g);  p.P3  = LD4(k0 + 3, g);
    return p;
}

__device__ __forceinline__ float4 upd_row(const Piv4& p, const float4 pan, float4 v) {
    const float f0 = pan.x * p.r0i;
    const float f1 = (pan.y - f0 * p.pp0.y) * p.r1i;
    const float f2 = (pan.z - f0 * p.pp0.z - f1 * p.pp1.z) * p.r2i;
    const float f3 = (pan.w - f0 * p.pp0.w - f1 * p.pp1.w - f2 * p.pp2.w) * p.r3i;
    v = fnma4(v, f0, p.P0); v = fnma4(v, f1, p.P1);
    v = fnma4(v, f2, p.P2); v = fnma4(v, f3, p.P3);
    return v;
}

// One workgroup per frequency block. Rank-4 blocked non-pivoted LU with
// LOOKAHEAD: per phase k0, wave 0 urgently sweeps rows k0+4..k0+7 and then
// immediately factors panel(k0+4) (all wave-local, DS in-order), while waves
// 1..3 sweep the bulk rows k0+8..99. ONE barrier per phase.
__global__ __launch_bounds__(256) void lu_logdet_kernel(const float* __restrict__ w,
                                                        const float* __restrict__ L,
                                                        float* __restrict__ out) {
    __shared__ float a[BLK * P];
    __shared__ float diag[BLK];
    __shared__ float ps[2];
    __shared__ int   pn[2];

    const int f    = blockIdx.x;
    const int tid  = threadIdx.x;
    const int wave = tid >> 6;
    const int lane = tid & 63;
    const int half = lane >> 5;
    const int g    = lane & 31;      // float4 column group, active if g < 25

    // ---- load diag block f, fused transform: M[r][c] = s_r*D[r][c] + (r==c ? 1-s_r : 0)
    const float* base = L + (size_t)f * BLK * NTOT + (size_t)f * BLK;
    for (int q = tid; q < BLK * 25; q += 256) {        // 25 float4 per row
        const int r  = q / 25;
        const int c0 = (q - r * 25) * 4;
        const float4 v = *reinterpret_cast<const float4*>(base + (size_t)r * NTOT + c0);
        const float sv = 1.0f / (1.0f + expf(-w[f * BLK + r]));
        const float ds = 1.0f - sv;
        float4 m;
        m.x = sv * v.x + ((c0 + 0) == r ? ds : 0.0f);
        m.y = sv * v.y + ((c0 + 1) == r ? ds : 0.0f);
        m.z = sv * v.z + ((c0 + 2) == r ? ds : 0.0f);
        m.w = sv * v.w + ((c0 + 3) == r ? ds : 0.0f);
        *reinterpret_cast<float4*>(&a[r * P + c0]) = m;
    }
    __syncthreads();

    // ---- prologue: factor panel(0)
    if (wave == 0 && lane < 25) panel4(a, diag, 0, lane);
    __syncthreads();

    // ---- main loop: 24 phases, 1 barrier each
    for (int k0 = 0; k0 <= 92; k0 += 4) {
        const int gp = k0 >> 2;
        if (wave == 0) {
            // urgent sweep: rows k0+4+half, k0+6+half (groups > gp)
            if (g > gp && g < 25) {
                const Piv4 pv = load_piv(a, k0, gp, g);
                const int i1 = k0 + 4 + half;
                const int i2 = k0 + 6 + half;
                const float4 pan1 = LD4(i1, gp);
                const float4 pan2 = LD4(i2, gp);
                float4 v1 = LD4(i1, g);
                float4 v2 = LD4(i2, g);
                v1 = upd_row(pv, pan1, v1);
                v2 = upd_row(pv, pan2, v2);
                LD4(i1, g) = v1;
                LD4(i2, g) = v2;
            }
            // lookahead panel on the rows just swept (wave-local)
            if (lane < 25) panel4(a, diag, k0 + 4, lane);
        } else {
            // bulk sweep: rows k0+8..99, 6 half-wave streams (stride 6)
            if (g > gp && g < 25) {
                const Piv4 pv = load_piv(a, k0, gp, g);
                int i = k0 + 8 + 2 * (wave - 1) + half;
                for (; i + 6 < BLK; i += 12) {
                    const int i2 = i + 6;
                    const float4 panA = LD4(i,  gp);
                    const float4 panB = LD4(i2, gp);
                    float4 vA = LD4(i,  g);
                    float4 vB = LD4(i2, g);
                    vA = upd_row(pv, panA, vA);
                    vB = upd_row(pv, panB, vB);
                    LD4(i,  g) = vA;
                    LD4(i2, g) = vB;
                }
                for (; i < BLK; i += 6) {
                    const float4 pan = LD4(i, gp);
                    float4 v = LD4(i, g);
                    v = upd_row(pv, pan, v);
                    LD4(i, g) = v;
                }
            }
        }
        __syncthreads();
    }

    // ---- logdet from U diagonal (shuffle reduction, 1 barrier)
    float lsum = 0.0f;
    int   lneg = 0;
    if (tid < BLK) {
        const float d = diag[tid];
        lsum = logf(fabsf(d));                   // d==0 -> -inf -> caught below
        lneg = (d < 0.0f) ? 1 : 0;
    }
    if (tid < 128) {
        for (int off = 32; off > 0; off >>= 1) {
            lsum += __shfl_down(lsum, off);
            lneg += __shfl_down(lneg, off);
        }
        if (lane == 0) { ps[wave] = lsum; pn[wave] = lneg; }
    }
    __syncthreads();
    if (tid == 0) {
        float ld = ps[0] + ps[1];
        const int n = pn[0] + pn[1];
        if ((n & 1) || !isfinite(ld)) ld = __int_as_float(0x7fc00000);  // NaN
        out[1 + f] = ld;
    }
}

// Sum the 128 logdets into out[0] (NaN propagates, matching jnp.sum of where(...))
__global__ __launch_bounds__(128) void sum_kernel(float* __restrict__ out) {
    const int t = threadIdx.x;
    float v = out[1 + t];
    v += __shfl_down(v, 32);
    v += __shfl_down(v, 16);
    v += __shfl_down(v, 8);
    v += __shfl_down(v, 4);
    v += __shfl_down(v, 2);
    v += __shfl_down(v, 1);
    __shared__ float ws2[2];
    if ((t & 63) == 0) ws2[t >> 6] = v;
    __syncthreads();
    if (t == 0) out[0] = ws2[0] + ws2[1];
}

extern "C" void kernel_launch(void* const* d_in, const int* in_sizes, int n_in,
                              void* d_out, int out_size, void* d_ws, size_t ws_size,
                              hipStream_t stream) {
    const float* w = (const float*)d_in[0];   // weights (12800,) f32
    const float* L = (const float*)d_in[1];   // L_kernel (12800,12800) f32
    float* out = (float*)d_out;               // [0]=sum, [1..128]=logdets
    lu_logdet_kernel<<<NF, 256, 0, stream>>>(w, L, out);
    sum_kernel<<<1, 128, 0, stream>>>(out);
}